// Round 1
// baseline (40775.150 us; speedup 1.0000x reference)
//
#include <hip/hip_runtime.h>
#include <stdint.h>

// ---------------------------------------------------------------------------
// StateTrackingRecurrentCell: B=8, S=2048, H=1024
//   out_seq[b,t] = LN_out(state_{t+1}),  final = state_S
//   state_{t+1} = (1-u)*state_t + u*tanh(xo_t + (r ⊙ LN_st(state_t)) @ Woh^T)
//   u = sigmoid(xu_t + ns @ Wuh^T),  r = sigmoid(xr_t + ns @ Wrh^T)
//   x?_t = LN_in(hidden[b,t]) @ W?x^T + b?   (precomputed GEMM, parallel)
// ---------------------------------------------------------------------------

#define Hd   1024
#define Bb   8
#define Ss   2048
#define BSr  (Bb * Ss)      // 16384 rows
#define NWG  64             // scan workgroups (<=256 CUs -> co-resident)
#define COLS 16             // output columns owned per scan WG
#define EPSf 1e-5f

typedef __attribute__((ext_vector_type(8))) short bf16x8;
typedef __attribute__((ext_vector_type(4))) float f32x4;

// workspace layout (bytes)
#define OFF_STATE 0u                                   // f32 [8][1024]  = 32KB
#define OFF_RN    32768u                               // bf16 frag buf  = 32KB
#define OFF_CNT   65536u                               // barrier counter
#define OFF_NH    131072u                              // bf16 [16384][1024] = 32MB
#define OFF_WCAT  (OFF_NH + (size_t)BSr * Hd * 2)      // bf16 [3072][1024]  = 6MB
#define OFF_XCAT  (OFF_WCAT + (size_t)3072 * Hd * 2)   // bf16 x-projections = 96MB

#define SCAN_LDS 131712      // 3x32KB weights + 32KB A-frags + st_own + mv

__device__ __forceinline__ unsigned f2bf(float f) {
  unsigned u = __float_as_uint(f);
  return (u + 0x7FFFu + ((u >> 16) & 1u)) >> 16;   // RNE f32->bf16
}
__device__ __forceinline__ float bf2f(unsigned short s) {
  return __uint_as_float(((unsigned)s) << 16);
}

// ---------------------------------------------------------------------------
// Kernel 1: input LN -> nh(bf16);  x-half weight convert -> Wcat(bf16);
//           state init + barrier counter zero.
// ---------------------------------------------------------------------------
__global__ __launch_bounds__(256) void k_prep(
    const float* __restrict__ hidden, const float* __restrict__ in_g,
    const float* __restrict__ in_b, const float* __restrict__ prev_state,
    const float* __restrict__ Wu, const float* __restrict__ Wr,
    const float* __restrict__ Wo,
    unsigned short* __restrict__ nh, unsigned short* __restrict__ Wcat,
    float* __restrict__ state_buf, unsigned* __restrict__ cnt)
{
  __shared__ float rs[4], rq[4], mvv[2];
  const int bx = blockIdx.x, tid = threadIdx.x;
  if (bx < BSr) {
    // one block per row: LayerNorm(hidden[row]) * in_g + in_b -> bf16
    float4 v = *(const float4*)(hidden + (size_t)bx * Hd + tid * 4);
    float s = v.x + v.y + v.z + v.w;
    float q = v.x * v.x + v.y * v.y + v.z * v.z + v.w * v.w;
#pragma unroll
    for (int m = 1; m < 64; m <<= 1) { s += __shfl_xor(s, m); q += __shfl_xor(q, m); }
    if ((tid & 63) == 0) { rs[tid >> 6] = s; rq[tid >> 6] = q; }
    __syncthreads();
    if (tid == 0) {
      float ts = rs[0] + rs[1] + rs[2] + rs[3];
      float tq = rq[0] + rq[1] + rq[2] + rq[3];
      float m = ts * (1.0f / Hd);
      mvv[0] = m;
      mvv[1] = rsqrtf(tq * (1.0f / Hd) - m * m + EPSf);
    }
    __syncthreads();
    float m = mvv[0], rstd = mvv[1];
    float4 g  = *(const float4*)(in_g + tid * 4);
    float4 b4 = *(const float4*)(in_b + tid * 4);
    unsigned r0 = f2bf((v.x - m) * rstd * g.x + b4.x);
    unsigned r1 = f2bf((v.y - m) * rstd * g.y + b4.y);
    unsigned r2 = f2bf((v.z - m) * rstd * g.z + b4.z);
    unsigned r3 = f2bf((v.w - m) * rstd * g.w + b4.w);
    uint2 pk; pk.x = r0 | (r1 << 16); pk.y = r2 | (r3 << 16);
    *(uint2*)(nh + (size_t)bx * Hd + tid * 4) = pk;
  } else if (bx < BSr + 3072) {
    // Wcat[q][k] = bf16(W_mat[i][k]) for k in [0,1024)  (x-side halves)
    const int q2 = bx - BSr;
    const float* W = (q2 < 1024) ? Wu : (q2 < 2048) ? Wr : Wo;
    const int i = q2 & 1023;
    float4 v = *(const float4*)(W + (size_t)i * 2048 + tid * 4);
    unsigned r0 = f2bf(v.x), r1 = f2bf(v.y), r2 = f2bf(v.z), r3 = f2bf(v.w);
    uint2 pk; pk.x = r0 | (r1 << 16); pk.y = r2 | (r3 << 16);
    *(uint2*)(Wcat + (size_t)q2 * Hd + tid * 4) = pk;
  } else {
    for (int j = tid; j < Bb * Hd; j += 256) state_buf[j] = prev_state[j];
    if (tid < 32) cnt[tid] = 0;
  }
}

// ---------------------------------------------------------------------------
// Kernel 2: xcat = nh @ Wcat^T + bias  (M=16384, N=3072, K=1024, bf16 MFMA)
// Output layout optimized for scan reads:
//   idx = ((t*64 + col/16)*3 + mat)*128 + b*16 + (col&15)   (bf16)
// ---------------------------------------------------------------------------
__global__ __launch_bounds__(256) void k_gemm(
    const unsigned short* __restrict__ nh, const unsigned short* __restrict__ Wcat,
    const float* __restrict__ bu, const float* __restrict__ br,
    const float* __restrict__ bo, unsigned short* __restrict__ xcat)
{
  __shared__ unsigned short aA[8 * 64 * 8];   // A-frags, linear per (rowtile,lane)
  __shared__ unsigned short aB[8 * 64 * 8];
  const int tid = threadIdx.x, bx = blockIdx.x;
  const int mt = bx & 127, nt = bx >> 7;      // 128 x 24 tiles of 128x128
  const int mb = mt * 128, nb = nt * 128;
  const int lane = tid & 63, wave = tid >> 6;
  const int wm = wave >> 1, wn = wave & 1;

  f32x4 acc[4][4];
  f32x4 zz = {0.f, 0.f, 0.f, 0.f};
#pragma unroll
  for (int mi = 0; mi < 4; ++mi)
#pragma unroll
    for (int ni = 0; ni < 4; ++ni) acc[mi][ni] = zz;

  for (int ks = 0; ks < 32; ++ks) {
    const int k0 = ks * 32;
#pragma unroll
    for (int it = 0; it < 4; ++it) {
      int gidx = tid + it * 256;
      int slot = gidx >> 6, l = gidx & 63;
      int kk = k0 + ((l >> 4) << 3);
      int r16 = slot & 7;
      if (slot < 8) {
        int row = mb + r16 * 16 + (l & 15);
        uint4 v = *(const uint4*)(nh + (size_t)row * Hd + kk);
        *(uint4*)(aA + (size_t)(r16 * 64 + l) * 8) = v;
      } else {
        int row = nb + r16 * 16 + (l & 15);
        uint4 v = *(const uint4*)(Wcat + (size_t)row * Hd + kk);
        *(uint4*)(aB + (size_t)(r16 * 64 + l) * 8) = v;
      }
    }
    __syncthreads();
    bf16x8 af_[4], bf_[4];
#pragma unroll
    for (int mi = 0; mi < 4; ++mi)
      af_[mi] = *(const bf16x8*)(aA + ((wm * 4 + mi) * 64 + lane) * 8);
#pragma unroll
    for (int ni = 0; ni < 4; ++ni)
      bf_[ni] = *(const bf16x8*)(aB + ((wn * 4 + ni) * 64 + lane) * 8);
#pragma unroll
    for (int mi = 0; mi < 4; ++mi)
#pragma unroll
      for (int ni = 0; ni < 4; ++ni)
        acc[mi][ni] = __builtin_amdgcn_mfma_f32_16x16x32_bf16(af_[mi], bf_[ni], acc[mi][ni], 0, 0, 0);
    __syncthreads();
  }

#pragma unroll
  for (int ni = 0; ni < 4; ++ni) {
    int n = nb + wn * 64 + ni * 16 + (lane & 15);
    int mat = n >> 10, col = n & 1023;
    float bias = (mat == 0) ? bu[col] : (mat == 1) ? br[col] : bo[col];
#pragma unroll
    for (int mi = 0; mi < 4; ++mi) {
#pragma unroll
      for (int ii = 0; ii < 4; ++ii) {
        int mrow = mb + wm * 64 + mi * 16 + ((lane >> 4) << 2) + ii;
        int b = mrow >> 11, t = mrow & 2047;
        size_t idx = ((size_t)(t * 64 + (col >> 4)) * 3 + mat) * 128 + b * 16 + (col & 15);
        xcat[idx] = (unsigned short)f2bf(acc[mi][ni][ii] + bias);
      }
    }
  }
}

// ---------------------------------------------------------------------------
// inter-WG barrier: monotonic counter, agent-scope atomics
// ---------------------------------------------------------------------------
__device__ __forceinline__ void gbar(unsigned* cnt, unsigned epoch) {
  __syncthreads();                      // drains this wave's vmem before arrive
  if (threadIdx.x == 0) {
    __hip_atomic_fetch_add(cnt, 1u, __ATOMIC_ACQ_REL, __HIP_MEMORY_SCOPE_AGENT);
    const unsigned need = epoch * NWG;
    while (__hip_atomic_load(cnt, __ATOMIC_RELAXED, __HIP_MEMORY_SCOPE_AGENT) < need) {
      __builtin_amdgcn_s_sleep(1);
    }
  }
  __syncthreads();
  __threadfence();                      // acquire: invalidate caches for fresh reads
}

// ---------------------------------------------------------------------------
// Kernel 3: persistent scan. 64 WGs x 256 threads. Each WG owns 16 output
// columns of Wuh/Wrh/Woh, resident in LDS in MFMA B-frag order.
// ---------------------------------------------------------------------------
__global__ __launch_bounds__(256, 1) void k_scan(
    const float* __restrict__ Wu, const float* __restrict__ Wr,
    const float* __restrict__ Wo,
    const float* __restrict__ st_g, const float* __restrict__ st_b,
    const float* __restrict__ out_g, const float* __restrict__ out_b,
    const unsigned short* __restrict__ xcat,
    float* __restrict__ state_buf, unsigned short* __restrict__ rn_frag,
    unsigned* __restrict__ cnt, float* __restrict__ out)
{
  extern __shared__ char smem[];
  unsigned short* wU = (unsigned short*)smem;          // [2048*8] bf16 = 32KB
  unsigned short* wR = wU + 2048 * 8;
  unsigned short* wO = wR + 2048 * 8;
  char*  afb    = (char*)(wO + 2048 * 8);              // 32KB A-frag buffer
  float* st_own = (float*)(afb + 32768);               // [128] state at owned cols
  float* mv     = st_own + 128;                        // [16] per-batch sum/sumsq

  const int tid = threadIdx.x;
  const int wg = blockIdx.x;
  const int colbase = wg * COLS;
  const int lane = tid & 63;
  const int wave = tid >> 6;
  const int bmy = tid >> 5;      // batch row this thread reduces (0..7)
  const int imy = tid & 31;      // k-chunk (32 elems) within the row
  const int k0my = imy * 32;

  // ---- one-time init: weight fragments into LDS (B-frag order, linear) ----
  for (int mtx = 0; mtx < 3; ++mtx) {
    const float* W = (mtx == 0) ? Wu : (mtx == 1) ? Wr : Wo;
    unsigned short* dst = (mtx == 0) ? wU : (mtx == 1) ? wR : wO;
    for (int s = tid; s < 2048; s += 256) {
      int ks = s >> 6, l = s & 63;
      int c = l & 15, kg = l >> 4;
      int k0 = ks * 32 + kg * 8;
      const float* src = W + (size_t)(colbase + c) * 2048 + 1024 + k0;
      float4 v0 = *(const float4*)(src);
      float4 v1 = *(const float4*)(src + 4);
      bf16x8 pk;
      pk[0] = (short)f2bf(v0.x); pk[1] = (short)f2bf(v0.y);
      pk[2] = (short)f2bf(v0.z); pk[3] = (short)f2bf(v0.w);
      pk[4] = (short)f2bf(v1.x); pk[5] = (short)f2bf(v1.y);
      pk[6] = (short)f2bf(v1.z); pk[7] = (short)f2bf(v1.w);
      *(bf16x8*)(dst + (size_t)s * 8) = pk;
    }
  }
  // zero A-frag rows 8..15 (padding batch rows) once; never rewritten
  for (int s = tid; s < 2048; s += 256) {
    int l = s & 63, ks = s >> 6;
    if ((l & 15) >= 8)
      *(uint4*)(afb + (((s * 16) ^ ((ks & 7) << 4)))) = make_uint4(0, 0, 0, 0);
  }
  // per-thread constants: st gamma/beta over this thread's fixed k-slice
  float stg[32], stb[32];
#pragma unroll
  for (int j = 0; j < 32; j += 4) {
    float4 g = *(const float4*)(st_g + k0my + j);
    stg[j] = g.x; stg[j + 1] = g.y; stg[j + 2] = g.z; stg[j + 3] = g.w;
    float4 b4 = *(const float4*)(st_b + k0my + j);
    stb[j] = b4.x; stb[j + 1] = b4.y; stb[j + 2] = b4.z; stb[j + 3] = b4.w;
  }
  float outg_my = 0.f, outb_my = 0.f, stgo = 0.f, stbo = 0.f;
  if (tid < 128) {
    int c = colbase + (tid & 15);
    outg_my = out_g[c]; outb_my = out_b[c];
  }
  if (wave == 1 && lane < 32) {
    int c = colbase + (lane & 15);
    stgo = st_g[c]; stbo = st_b[c];
  }
  __syncthreads();

  unsigned epoch = 0;
  float uv[4] = {0.f, 0.f, 0.f, 0.f};

  for (int t = 0; t < Ss; ++t) {
    // prefetch x-projections for this step (independent of state)
    float xu[4] = {0, 0, 0, 0}, xo[4] = {0, 0, 0, 0}, xr[4] = {0, 0, 0, 0};
    if (lane < 32) {
      int b4i = (lane >> 4) * 4, c = lane & 15;
      size_t base = ((size_t)(t * 64 + wg) * 3) * 128;
      if (wave == 0) {
#pragma unroll
        for (int i = 0; i < 4; ++i) {
          xu[i] = bf2f(xcat[base + 0 * 128 + (b4i + i) * 16 + c]);
          xo[i] = bf2f(xcat[base + 2 * 128 + (b4i + i) * 16 + c]);
        }
      } else if (wave == 1) {
#pragma unroll
        for (int i = 0; i < 4; ++i)
          xr[i] = bf2f(xcat[base + 1 * 128 + (b4i + i) * 16 + c]);
      }
    }

    // ---- phase A: state load + per-batch mean/var ----
    float sv[32];
    {
      const float* sp = state_buf + bmy * Hd + k0my;
#pragma unroll
      for (int j = 0; j < 32; j += 4) {
        float4 v = *(const float4*)(sp + j);
        sv[j] = v.x; sv[j + 1] = v.y; sv[j + 2] = v.z; sv[j + 3] = v.w;
      }
    }
    float s = 0.f, q = 0.f;
#pragma unroll
    for (int j = 0; j < 32; ++j) { s += sv[j]; q += sv[j] * sv[j]; }
#pragma unroll
    for (int m = 1; m < 32; m <<= 1) { s += __shfl_xor(s, m); q += __shfl_xor(q, m); }
    if (imy == 0) { mv[bmy * 2] = s; mv[bmy * 2 + 1] = q; }
    __syncthreads();

    // output write for step t-1 + stash state at owned cols
    if (tid < 128) {
      int b = tid >> 4, c = tid & 15;
      float sval = state_buf[b * Hd + colbase + c];
      st_own[tid] = sval;
      float m = mv[b * 2] * (1.0f / Hd);
      float rstd = rsqrtf(mv[b * 2 + 1] * (1.0f / Hd) - m * m + EPSf);
      if (t > 0)
        out[(size_t)b * Ss * Hd + (size_t)(t - 1) * Hd + colbase + c] =
            (sval - m) * rstd * outg_my + outb_my;
    }

    // build ns A-fragments (bf16, XOR-swizzled LDS)
    {
      float m = mv[bmy * 2] * (1.0f / Hd);
      float rstd = rsqrtf(mv[bmy * 2 + 1] * (1.0f / Hd) - m * m + EPSf);
#pragma unroll
      for (int kg = 0; kg < 4; ++kg) {
        bf16x8 pk;
#pragma unroll
        for (int j = 0; j < 8; ++j) {
          float f = (sv[kg * 8 + j] - m) * rstd * stg[kg * 8 + j] + stb[kg * 8 + j];
          pk[j] = (short)f2bf(f);
        }
        int sidx = imy * 64 + kg * 16 + bmy;
        *(bf16x8*)(afb + ((sidx * 16) ^ ((imy & 7) << 4))) = pk;
      }
    }
    __syncthreads();

    // MFMA: wave0 -> u, wave1 -> r (+ r*ns exchange)
    if (wave < 2) {
      const unsigned short* wsel = (wave == 0) ? wU : wR;
      f32x4 acc = {0.f, 0.f, 0.f, 0.f};
#pragma unroll 4
      for (int ks = 0; ks < 32; ++ks) {
        bf16x8 a = *(const bf16x8*)(afb + (((ks * 64 + lane) * 16) ^ ((ks & 7) << 4)));
        bf16x8 w8 = *(const bf16x8*)(wsel + (size_t)(ks * 64 + lane) * 8);
        acc = __builtin_amdgcn_mfma_f32_16x16x32_bf16(a, w8, acc, 0, 0, 0);
      }
      if (lane < 32) {
        int c = lane & 15;
#pragma unroll
        for (int i = 0; i < 4; ++i) {
          int b = (lane >> 4) * 4 + i;
          if (wave == 0) {
            float pre = acc[i] + xu[i];
            uv[i] = 1.0f / (1.0f + __expf(-pre));
          } else {
            float pre = acc[i] + xr[i];
            float rvv = 1.0f / (1.0f + __expf(-pre));
            float m = mv[b * 2] * (1.0f / Hd);
            float rstd = rsqrtf(mv[b * 2 + 1] * (1.0f / Hd) - m * m + EPSf);
            float nso = (st_own[b * 16 + c] - m) * rstd * stgo + stbo;
            float rn = rvv * nso;
            int k = colbase + c;
            int ks2 = k >> 5, kg2 = (k >> 3) & 3, j2 = k & 7;
            rn_frag[(size_t)((ks2 * 64 + kg2 * 16 + b) * 8 + j2)] =
                (unsigned short)f2bf(rn);
          }
        }
      }
    }
    gbar(cnt, ++epoch);

    // ---- phase B: gather r*ns frags, candidate MFMA, state update ----
    for (int qq = tid; qq < 1024; qq += 256) {
      int ks = qq >> 5, kg = (qq >> 3) & 3, b = qq & 7;
      int sidx = ks * 64 + kg * 16 + b;
      uint4 v = *(const uint4*)(rn_frag + (size_t)sidx * 8);
      *(uint4*)(afb + ((sidx * 16) ^ ((ks & 7) << 4))) = v;
    }
    __syncthreads();

    if (wave == 0) {
      f32x4 acc = {0.f, 0.f, 0.f, 0.f};
#pragma unroll 4
      for (int ks = 0; ks < 32; ++ks) {
        bf16x8 a = *(const bf16x8*)(afb + (((ks * 64 + lane) * 16) ^ ((ks & 7) << 4)));
        bf16x8 w8 = *(const bf16x8*)(wO + (size_t)(ks * 64 + lane) * 8);
        acc = __builtin_amdgcn_mfma_f32_16x16x32_bf16(a, w8, acc, 0, 0, 0);
      }
      if (lane < 32) {
        int c = lane & 15;
#pragma unroll
        for (int i = 0; i < 4; ++i) {
          int b = (lane >> 4) * 4 + i;
          float pre = acc[i] + xo[i];
          float cd = tanhf(pre);
          float sold = st_own[b * 16 + c];
          float nsv = (1.0f - uv[i]) * sold + uv[i] * cd;
          state_buf[b * Hd + colbase + c] = nsv;
        }
      }
    }
    gbar(cnt, ++epoch);
  }

  // ---- epilogue: out[S-1] + final_state ----
  {
    const float* sp = state_buf + bmy * Hd + k0my;
    float s = 0.f, q = 0.f;
#pragma unroll
    for (int j = 0; j < 32; j += 4) {
      float4 v = *(const float4*)(sp + j);
      s += v.x + v.y + v.z + v.w;
      q += v.x * v.x + v.y * v.y + v.z * v.z + v.w * v.w;
    }
#pragma unroll
    for (int m = 1; m < 32; m <<= 1) { s += __shfl_xor(s, m); q += __shfl_xor(q, m); }
    if (imy == 0) { mv[bmy * 2] = s; mv[bmy * 2 + 1] = q; }
    __syncthreads();
    if (tid < 128) {
      int b = tid >> 4, c = tid & 15;
      float sval = state_buf[b * Hd + colbase + c];
      float m = mv[b * 2] * (1.0f / Hd);
      float rstd = rsqrtf(mv[b * 2 + 1] * (1.0f / Hd) - m * m + EPSf);
      out[(size_t)b * Ss * Hd + (size_t)(Ss - 1) * Hd + colbase + c] =
          (sval - m) * rstd * outg_my + outb_my;
      out[(size_t)Bb * Ss * Hd + b * Hd + colbase + c] = sval;
    }
  }
}

// ---------------------------------------------------------------------------
extern "C" void kernel_launch(void* const* d_in, const int* in_sizes, int n_in,
                              void* d_out, int out_size, void* d_ws, size_t ws_size,
                              hipStream_t stream) {
  const float* hidden = (const float*)d_in[0];
  const float* prev   = (const float*)d_in[1];
  const float* in_g   = (const float*)d_in[2];
  const float* in_b   = (const float*)d_in[3];
  const float* st_g   = (const float*)d_in[4];
  const float* st_b   = (const float*)d_in[5];
  const float* out_g  = (const float*)d_in[6];
  const float* out_b  = (const float*)d_in[7];
  const float* Wu     = (const float*)d_in[8];
  const float* bu     = (const float*)d_in[9];
  const float* Wr     = (const float*)d_in[10];
  const float* br     = (const float*)d_in[11];
  const float* Wo     = (const float*)d_in[12];
  const float* bo     = (const float*)d_in[13];

  char* ws = (char*)d_ws;
  float*          state_buf = (float*)(ws + OFF_STATE);
  unsigned short* rn_frag   = (unsigned short*)(ws + OFF_RN);
  unsigned*       cnt       = (unsigned*)(ws + OFF_CNT);
  unsigned short* nh        = (unsigned short*)(ws + OFF_NH);
  unsigned short* Wcat      = (unsigned short*)(ws + OFF_WCAT);
  unsigned short* xcat      = (unsigned short*)(ws + OFF_XCAT);
  float*          out       = (float*)d_out;

  static int attr_done = 0;
  (void)hipFuncSetAttribute(reinterpret_cast<const void*>(k_scan),
                            hipFuncAttributeMaxDynamicSharedMemorySize, SCAN_LDS);
  (void)attr_done;

  k_prep<<<dim3(BSr + 3072 + 1), dim3(256), 0, stream>>>(
      hidden, in_g, in_b, prev, Wu, Wr, Wo, nh, Wcat, state_buf, cnt);
  k_gemm<<<dim3(3072), dim3(256), 0, stream>>>(nh, Wcat, bu, br, bo, xcat);
  k_scan<<<dim3(NWG), dim3(256), SCAN_LDS, stream>>>(
      Wu, Wr, Wo, st_g, st_b, out_g, out_b, xcat, state_buf, rn_frag, cnt, out);
}